// Round 1
// baseline (712.161 us; speedup 1.0000x reference)
//
#include <hip/hip_runtime.h>

#define N_NODES 50000
#define N_EDGES 800000
constexpr float EPSV = 1e-5f;

__device__ __forceinline__ float bf2f(unsigned short u) {
    return __uint_as_float(((unsigned int)u) << 16);
}
__device__ __forceinline__ unsigned short f2bf(float f) {
    unsigned int x = __float_as_uint(f);
    unsigned int r = x + 0x7FFFu + ((x >> 16) & 1u);
    return (unsigned short)(r >> 16);
}

// ---------------- CSR build ----------------
__global__ void k_count(const int* __restrict__ dst, int* __restrict__ deg) {
    int e = blockIdx.x * 256 + threadIdx.x;
    if (e < N_EDGES) atomicAdd(&deg[dst[e]], 1);
}

__global__ void k_scan(const int* __restrict__ deg, int* __restrict__ rowptr) {
    __shared__ int buf[1024];
    __shared__ int sbase;
    int tid = threadIdx.x;
    if (tid == 0) { sbase = 0; rowptr[0] = 0; }
    __syncthreads();
    for (int start = 0; start < N_NODES; start += 1024) {
        int i = start + tid;
        int v = (i < N_NODES) ? deg[i] : 0;
        buf[tid] = v;
        __syncthreads();
        for (int off = 1; off < 1024; off <<= 1) {
            int t = (tid >= off) ? buf[tid - off] : 0;
            __syncthreads();
            buf[tid] += t;
            __syncthreads();
        }
        int b = sbase;
        if (i < N_NODES) rowptr[i + 1] = b + buf[tid];
        __syncthreads();
        if (tid == 1023) sbase = b + buf[1023];
        __syncthreads();
    }
}

__global__ void k_initpos(const int* __restrict__ rowptr, int* __restrict__ pos) {
    int i = blockIdx.x * 256 + threadIdx.x;
    if (i < N_NODES) pos[i] = rowptr[i];
}

__global__ void k_scatter(const int* __restrict__ src, const int* __restrict__ dst,
                          int* __restrict__ pos, int* __restrict__ csr) {
    int e = blockIdx.x * 256 + threadIdx.x;
    if (e < N_EDGES) {
        int d = dst[e];
        int p = atomicAdd(&pos[d], 1);
        csr[p] = src[e];
    }
}

// ---------------- mean aggregation: one wave per node ----------------
template <int D, bool IN_BF16>
__global__ void k_aggregate(const void* __restrict__ hin, const int* __restrict__ rowptr,
                            const int* __restrict__ csr, unsigned short* __restrict__ out) {
    constexpr int VPL = D / 64;  // floats per lane (2 or 4)
    int lane = threadIdx.x & 63;
    int wv = threadIdx.x >> 6;
    int node = blockIdx.x * 4 + wv;
    if (node >= N_NODES) return;
    int s0 = rowptr[node], s1 = rowptr[node + 1];
    float acc[VPL];
#pragma unroll
    for (int i = 0; i < VPL; i++) acc[i] = 0.f;

    if constexpr (IN_BF16) {
        const unsigned short* h = (const unsigned short*)hin;
        for (int e = s0; e < s1; e++) {
            int s = csr[e];
            const unsigned short* row = h + (size_t)s * D + lane * VPL;
            if constexpr (VPL == 2) {
                ushort2 u = *(const ushort2*)row;
                acc[0] += bf2f(u.x); acc[1] += bf2f(u.y);
            } else {
                ushort4 u = *(const ushort4*)row;
                acc[0] += bf2f(u.x); acc[1] += bf2f(u.y);
                acc[2] += bf2f(u.z); acc[3] += bf2f(u.w);
            }
        }
    } else {
        const float* h = (const float*)hin;
        for (int e = s0; e < s1; e++) {
            int s = csr[e];
            const float* row = h + (size_t)s * D + lane * VPL;
            if constexpr (VPL == 2) {
                float2 u = *(const float2*)row;
                acc[0] += u.x; acc[1] += u.y;
            } else {
                float4 u = *(const float4*)row;
                acc[0] += u.x; acc[1] += u.y; acc[2] += u.z; acc[3] += u.w;
            }
        }
    }
    float inv = 1.f / (float)max(s1 - s0, 1);
    unsigned short* o = out + (size_t)node * D + lane * VPL;
#pragma unroll
    for (int i = 0; i < VPL; i++) o[i] = f2bf(acc[i] * inv);
}

// ---------------- weight folding (BN + skip folded into GEMM weights) ----------------
__global__ void k_prep1(const float* __restrict__ Wp, const float* __restrict__ bp,
                        const float* __restrict__ W1l, const float* __restrict__ b1l,
                        const float* __restrict__ W1r, const float* __restrict__ g,
                        const float* __restrict__ b, const float* __restrict__ m,
                        const float* __restrict__ v, float* __restrict__ Wc,
                        float* __restrict__ c) {
    int idx = blockIdx.x * 256 + threadIdx.x;
    if (idx >= 256 * 256) return;
    int k = idx >> 8, j = idx & 255;
    float A = g[j] * rsqrtf(v[j] + EPSV);
    float w;
    if (k < 128) w = W1l[k * 256 + j] * A;
    else         w = W1r[(k - 128) * 256 + j] * A + Wp[(k - 128) * 256 + j];
    Wc[idx] = w;
    if (k == 0) c[j] = b1l[j] * A + (b[j] - m[j] * A) + bp[j];
}

__global__ void k_prep2(const float* __restrict__ Wsk, const float* __restrict__ bsk,
                        const float* __restrict__ W2l, const float* __restrict__ b2l,
                        const float* __restrict__ W2r, const float* __restrict__ g,
                        const float* __restrict__ b, const float* __restrict__ m,
                        const float* __restrict__ v, float* __restrict__ Wc,
                        float* __restrict__ c) {
    int idx = blockIdx.x * 256 + threadIdx.x;
    if (idx >= 512 * 128) return;
    int k = idx >> 7, j = idx & 127;
    float A = g[j] * rsqrtf(v[j] + EPSV);
    float w;
    if (k < 256) w = W2l[k * 128 + j] * A;
    else         w = W2r[(k - 256) * 128 + j] * A + Wsk[(k - 256) * 128 + j];
    Wc[idx] = w;
    if (k == 0) c[j] = b2l[j] * A + (b[j] - m[j] * A) + bsk[j];
}

__global__ void k_prep3(const float* __restrict__ W3l, const float* __restrict__ b3l,
                        const float* __restrict__ W3r, float* __restrict__ Wc,
                        float* __restrict__ c) {
    int idx = blockIdx.x * 256 + threadIdx.x;
    if (idx >= 256 * 64) return;
    int k = idx >> 6, j = idx & 63;
    Wc[idx] = (k < 128) ? W3l[k * 64 + j] : W3r[(k - 128) * 64 + j];
    if (k == 0) c[j] = b3l[j];
}

// ---------------- fused GEMM: Out = act([A1 | A2] @ W + bias) ----------------
template <int BM, int LDA, bool ABF>
__device__ __forceinline__ void stageA(const void* __restrict__ Aptr, int K, int m0, int kloc,
                                       float* __restrict__ As, int tid) {
    // load BM x 32 tile; each iteration loads 4 consecutive elements
    for (int i = tid; i < BM * 8; i += 256) {
        int r = i >> 3;
        int col = (i & 7) * 4;
        int gm = m0 + r;
        float f0, f1, f2, f3;
        if (gm < N_NODES) {
            if constexpr (ABF) {
                const unsigned short* p = (const unsigned short*)Aptr + (size_t)gm * K + kloc + col;
                ushort4 u = *(const ushort4*)p;
                f0 = bf2f(u.x); f1 = bf2f(u.y); f2 = bf2f(u.z); f3 = bf2f(u.w);
            } else {
                const float* p = (const float*)Aptr + (size_t)gm * K + kloc + col;
                float4 u = *(const float4*)p;
                f0 = u.x; f1 = u.y; f2 = u.z; f3 = u.w;
            }
        } else {
            f0 = f1 = f2 = f3 = 0.f;
        }
        float* d = &As[r * LDA + col];
        d[0] = f0; d[1] = f1; d[2] = f2; d[3] = f3;
    }
}

template <int K1, int K2, int NOUT, int BM, bool A1BF, bool A2BF, bool RELU, bool OUTBF>
__global__ __launch_bounds__(256) void k_gemm(const void* __restrict__ A1,
                                              const void* __restrict__ A2,
                                              const float* __restrict__ W,
                                              const float* __restrict__ bias,
                                              void* __restrict__ Out) {
    constexpr int BK = 32;
    constexpr int TXC = NOUT / 16;   // threads across columns
    constexpr int TYC = 256 / TXC;   // threads across rows
    constexpr int VM = BM / TYC;     // rows per thread
    constexpr int LDA = BK + 1;      // 33: conflict-free A reads
    constexpr int QW = NOUT / 4;     // column-group stride

    __shared__ float As[BM * LDA];
    __shared__ float Ws[BK * NOUT];

    int tid = threadIdx.x;
    int tx = tid % TXC, ty = tid / TXC;
    int m0 = blockIdx.x * BM;

    float acc[VM][16];
#pragma unroll
    for (int i = 0; i < VM; i++)
#pragma unroll
        for (int j = 0; j < 16; j++) acc[i][j] = 0.f;

    constexpr int NT = (K1 + K2) / BK;
    for (int t = 0; t < NT; t++) {
        int kglob = t * BK;
        __syncthreads();
        // stage W tile [BK][NOUT]
        for (int i = tid; i < BK * NOUT / 4; i += 256) {
            int r = i / (NOUT / 4);
            int c4 = (i % (NOUT / 4)) * 4;
            *(float4*)&Ws[r * NOUT + c4] = *(const float4*)&W[(size_t)(kglob + r) * NOUT + c4];
        }
        // stage A tile [BM][BK]
        if (kglob < K1) stageA<BM, LDA, A1BF>(A1, K1, m0, kglob, As, tid);
        else            stageA<BM, LDA, A2BF>(A2, K2, m0, kglob - K1, As, tid);
        __syncthreads();

#pragma unroll 4
        for (int kk = 0; kk < BK; kk++) {
            float4 wq[4];
#pragma unroll
            for (int q = 0; q < 4; q++)
                wq[q] = *(float4*)&Ws[kk * NOUT + q * QW + tx * 4];
            float av[VM];
#pragma unroll
            for (int i = 0; i < VM; i++) av[i] = As[(ty * VM + i) * LDA + kk];
#pragma unroll
            for (int i = 0; i < VM; i++) {
#pragma unroll
                for (int q = 0; q < 4; q++) {
                    acc[i][q * 4 + 0] += av[i] * wq[q].x;
                    acc[i][q * 4 + 1] += av[i] * wq[q].y;
                    acc[i][q * 4 + 2] += av[i] * wq[q].z;
                    acc[i][q * 4 + 3] += av[i] * wq[q].w;
                }
            }
        }
    }

    // epilogue: bias (+relu), store
    float4 bq[4];
#pragma unroll
    for (int q = 0; q < 4; q++) bq[q] = *(const float4*)&bias[q * QW + tx * 4];
#pragma unroll
    for (int i = 0; i < VM; i++) {
        int gm = m0 + ty * VM + i;
        if (gm >= N_NODES) break;
#pragma unroll
        for (int q = 0; q < 4; q++) {
            float v0 = acc[i][q * 4 + 0] + bq[q].x;
            float v1 = acc[i][q * 4 + 1] + bq[q].y;
            float v2 = acc[i][q * 4 + 2] + bq[q].z;
            float v3 = acc[i][q * 4 + 3] + bq[q].w;
            if (RELU) {
                v0 = fmaxf(v0, 0.f); v1 = fmaxf(v1, 0.f);
                v2 = fmaxf(v2, 0.f); v3 = fmaxf(v3, 0.f);
            }
            int col = q * QW + tx * 4;
            if constexpr (OUTBF) {
                ushort4 pk = make_ushort4(f2bf(v0), f2bf(v1), f2bf(v2), f2bf(v3));
                *(ushort4*)&((unsigned short*)Out)[(size_t)gm * NOUT + col] = pk;
            } else {
                *(float4*)&((float*)Out)[(size_t)gm * NOUT + col] = make_float4(v0, v1, v2, v3);
            }
        }
    }
}

// ---------------- classifier ----------------
__global__ void k_logits(const float* __restrict__ emb, const float* __restrict__ Wc,
                         const float* __restrict__ bc, float* __restrict__ logits) {
    __shared__ float wc[128];
    int tid = threadIdx.x;
    if (tid < 128) wc[tid] = Wc[tid];
    __syncthreads();
    int r = blockIdx.x * 256 + tid;
    if (r >= N_NODES) return;
    const float* e = emb + (size_t)r * 64;
    float l0 = bc[0], l1 = bc[1];
#pragma unroll
    for (int j0 = 0; j0 < 64; j0 += 4) {
        float4 v = *(const float4*)&e[j0];
        l0 += v.x * wc[2 * j0 + 0] + v.y * wc[2 * j0 + 2] + v.z * wc[2 * j0 + 4] + v.w * wc[2 * j0 + 6];
        l1 += v.x * wc[2 * j0 + 1] + v.y * wc[2 * j0 + 3] + v.z * wc[2 * j0 + 5] + v.w * wc[2 * j0 + 7];
    }
    ((float2*)logits)[r] = make_float2(l0, l1);
}

extern "C" void kernel_launch(void* const* d_in, const int* in_sizes, int n_in,
                              void* d_out, int out_size, void* d_ws, size_t ws_size,
                              hipStream_t stream) {
    const float* x    = (const float*)d_in[0];
    const int*   ei   = (const int*)d_in[1];
    const float* Wp   = (const float*)d_in[2];
    const float* bp   = (const float*)d_in[3];
    const float* W1l  = (const float*)d_in[4];
    const float* b1l  = (const float*)d_in[5];
    const float* W1r  = (const float*)d_in[6];
    const float* bn1g = (const float*)d_in[7];
    const float* bn1b = (const float*)d_in[8];
    const float* bn1m = (const float*)d_in[9];
    const float* bn1v = (const float*)d_in[10];
    const float* Wsk  = (const float*)d_in[11];
    const float* bsk  = (const float*)d_in[12];
    const float* W2l  = (const float*)d_in[13];
    const float* b2l  = (const float*)d_in[14];
    const float* W2r  = (const float*)d_in[15];
    const float* bn2g = (const float*)d_in[16];
    const float* bn2b = (const float*)d_in[17];
    const float* bn2m = (const float*)d_in[18];
    const float* bn2v = (const float*)d_in[19];
    const float* W3l  = (const float*)d_in[20];
    const float* b3l  = (const float*)d_in[21];
    const float* W3r  = (const float*)d_in[22];
    const float* Wc   = (const float*)d_in[23];
    const float* bc   = (const float*)d_in[24];

    const int* src = ei;
    const int* dst = ei + N_EDGES;

    char* ws = (char*)d_ws;
    size_t o = 0;
    auto alloc = [&](size_t b) -> char* {
        char* p = ws + o;
        o = (o + b + 255) & ~(size_t)255;
        return p;
    };
    int* rowptr = (int*)alloc((N_NODES + 1) * 4);
    int* pos    = (int*)alloc((size_t)N_NODES * 4);
    int* csr    = (int*)alloc((size_t)N_EDGES * 4);
    unsigned short* meanb = (unsigned short*)alloc((size_t)N_NODES * 256 * 2);
    unsigned short* h1    = (unsigned short*)alloc((size_t)N_NODES * 256 * 2);
    unsigned short* h2    = (unsigned short*)alloc((size_t)N_NODES * 128 * 2);
    float* W1c = (float*)alloc(256 * 256 * 4);
    float* c1  = (float*)alloc(256 * 4);
    float* W2c = (float*)alloc(512 * 128 * 4);
    float* c2  = (float*)alloc(128 * 4);
    float* W3c = (float*)alloc(256 * 64 * 4);
    float* c3  = (float*)alloc(64 * 4);

    float* logits = (float*)d_out;
    float* emb    = (float*)d_out + (size_t)N_NODES * 2;

    // CSR build
    hipMemsetAsync(pos, 0, (size_t)N_NODES * 4, stream);
    k_count<<<3125, 256, 0, stream>>>(dst, pos);
    k_scan<<<1, 1024, 0, stream>>>(pos, rowptr);
    k_initpos<<<196, 256, 0, stream>>>(rowptr, pos);
    k_scatter<<<3125, 256, 0, stream>>>(src, dst, pos, csr);

    // weight folding
    k_prep1<<<256, 256, 0, stream>>>(Wp, bp, W1l, b1l, W1r, bn1g, bn1b, bn1m, bn1v, W1c, c1);
    k_prep2<<<256, 256, 0, stream>>>(Wsk, bsk, W2l, b2l, W2r, bn2g, bn2b, bn2m, bn2v, W2c, c2);
    k_prep3<<<64, 256, 0, stream>>>(W3l, b3l, W3r, W3c, c3);

    // layer 1: mean(x) ; h1 = relu([mean|x] @ W1c + c1)   (K=128+128 -> 256)
    k_aggregate<128, false><<<12500, 256, 0, stream>>>((const void*)x, rowptr, csr, meanb);
    k_gemm<128, 128, 256, 64, true, false, true, true><<<782, 256, 0, stream>>>(
        (const void*)meanb, (const void*)x, W1c, c1, (void*)h1);

    // layer 2: mean(h1) ; h2 = relu([mean|h1] @ W2c + c2) (K=256+256 -> 128)
    k_aggregate<256, true><<<12500, 256, 0, stream>>>((const void*)h1, rowptr, csr, meanb);
    k_gemm<256, 256, 128, 128, true, true, true, true><<<391, 256, 0, stream>>>(
        (const void*)meanb, (const void*)h1, W2c, c2, (void*)h2);

    // layer 3: mean(h2) ; emb = [mean|h2] @ W3c + c3      (K=128+128 -> 64, f32 out)
    k_aggregate<128, true><<<12500, 256, 0, stream>>>((const void*)h2, rowptr, csr, meanb);
    k_gemm<128, 128, 64, 128, true, true, false, false><<<391, 256, 0, stream>>>(
        (const void*)meanb, (const void*)h2, W3c, c3, (void*)emb);

    // classifier
    k_logits<<<196, 256, 0, stream>>>(emb, Wc, bc, logits);
}

// Round 2
// 513.942 us; speedup vs baseline: 1.3857x; 1.3857x over previous
//
#include <hip/hip_runtime.h>

#define NN 50000
#define NE 800000
constexpr float EPSV = 1e-5f;

typedef __attribute__((ext_vector_type(8))) short short8;
typedef __attribute__((ext_vector_type(4))) float f32x4;

__device__ __forceinline__ float bf2f(unsigned short u) {
    return __uint_as_float(((unsigned int)u) << 16);
}
__device__ __forceinline__ unsigned short f2bf(float f) {
    unsigned int x = __float_as_uint(f);
    return (unsigned short)((x + 0x7FFFu + ((x >> 16) & 1u)) >> 16);
}

// ---------------- CSR build ----------------
__global__ void k_count(const int* __restrict__ dst, int* __restrict__ deg) {
    int e = blockIdx.x * 256 + threadIdx.x;
    if (e < NE) atomicAdd(&deg[dst[e]], 1);
}

// single-block chunked scan: deg[0..NN) -> rowptr[0..NN]
__global__ void k_scan(const int* __restrict__ deg, int* __restrict__ rowptr) {
    __shared__ int sums[1024];
    int tid = threadIdx.x;
    constexpr int CH = (NN + 1023) / 1024;  // 49
    int base = tid * CH;
    int s = 0;
    for (int j = 0; j < CH; j++) {
        int i = base + j;
        if (i < NN) s += deg[i];
    }
    sums[tid] = s;
    __syncthreads();
    for (int off = 1; off < 1024; off <<= 1) {
        int t = (tid >= off) ? sums[tid - off] : 0;
        __syncthreads();
        sums[tid] += t;
        __syncthreads();
    }
    int run = (tid > 0) ? sums[tid - 1] : 0;
    if (tid == 0) rowptr[0] = 0;
    for (int j = 0; j < CH; j++) {
        int i = base + j;
        if (i < NN) {
            run += deg[i];
            rowptr[i + 1] = run;
        }
    }
}

__global__ void k_initpos(const int* __restrict__ rowptr, int* __restrict__ pos) {
    int i = blockIdx.x * 256 + threadIdx.x;
    if (i < NN) pos[i] = rowptr[i];
}

__global__ void k_scatter(const int* __restrict__ src, const int* __restrict__ dst,
                          int* __restrict__ pos, int* __restrict__ csr) {
    int e = blockIdx.x * 256 + threadIdx.x;
    if (e < NE) {
        int p = atomicAdd(&pos[dst[e]], 1);
        csr[p] = src[e];
    }
}

// ---------------- x -> bf16 ----------------
__global__ void k_xcast(const float* __restrict__ x, unsigned short* __restrict__ xb) {
    int i = blockIdx.x * 256 + threadIdx.x;
    if (i >= NN * 128 / 4) return;
    float4 v = ((const float4*)x)[i];
    ushort4 u = make_ushort4(f2bf(v.x), f2bf(v.y), f2bf(v.z), f2bf(v.w));
    ((ushort4*)xb)[i] = u;
}

// ---------------- weight prep: fold BN+skip, store bf16 in MFMA B-fragment layout
// Wf layout: [nb][kt][f][lane][8j]; col = nb*64 + f*16 + (lane&15), k = kt*32 + (lane>>4)*8 + j
__global__ void k_prep1(const float* __restrict__ Wp, const float* __restrict__ bp,
                        const float* __restrict__ W1l, const float* __restrict__ b1l,
                        const float* __restrict__ W1r, const float* __restrict__ g,
                        const float* __restrict__ b, const float* __restrict__ m,
                        const float* __restrict__ v, unsigned short* __restrict__ Wf,
                        float* __restrict__ c) {
    int t = blockIdx.x * 256 + threadIdx.x;  // K=128, NOUT=512 -> 8192 threads
    if (t >= 8192) return;
    int lane = t & 63, f = (t >> 6) & 3, kt = (t >> 8) & 3, nb = t >> 10;
    int col = nb * 64 + f * 16 + (lane & 15);
    int k0 = kt * 32 + (lane >> 4) * 8;
    unsigned short* o = Wf + (size_t)t * 8;
    if (col < 256) {  // P block: W1l * A
        float A = g[col] * rsqrtf(v[col] + EPSV);
        for (int j = 0; j < 8; j++) o[j] = f2bf(W1l[(k0 + j) * 256 + col] * A);
    } else {          // R block: W1r * A + Wp
        int cc = col - 256;
        float A = g[cc] * rsqrtf(v[cc] + EPSV);
        for (int j = 0; j < 8; j++)
            o[j] = f2bf(W1r[(k0 + j) * 256 + cc] * A + Wp[(k0 + j) * 256 + cc]);
    }
    if (t < 256) {
        float A = g[t] * rsqrtf(v[t] + EPSV);
        c[t] = b1l[t] * A + (b[t] - m[t] * A) + bp[t];
    }
}

__global__ void k_prep2(const float* __restrict__ Wsk, const float* __restrict__ bsk,
                        const float* __restrict__ W2l, const float* __restrict__ b2l,
                        const float* __restrict__ W2r, const float* __restrict__ g,
                        const float* __restrict__ b, const float* __restrict__ m,
                        const float* __restrict__ v, unsigned short* __restrict__ Wf,
                        float* __restrict__ c) {
    int t = blockIdx.x * 256 + threadIdx.x;  // K=256, NOUT=256 -> 8192 threads
    if (t >= 8192) return;
    int lane = t & 63, f = (t >> 6) & 3, kt = (t >> 8) & 7, nb = t >> 11;
    int col = nb * 64 + f * 16 + (lane & 15);
    int k0 = kt * 32 + (lane >> 4) * 8;
    unsigned short* o = Wf + (size_t)t * 8;
    if (col < 128) {
        float A = g[col] * rsqrtf(v[col] + EPSV);
        for (int j = 0; j < 8; j++) o[j] = f2bf(W2l[(k0 + j) * 128 + col] * A);
    } else {
        int cc = col - 128;
        float A = g[cc] * rsqrtf(v[cc] + EPSV);
        for (int j = 0; j < 8; j++)
            o[j] = f2bf(W2r[(k0 + j) * 128 + cc] * A + Wsk[(k0 + j) * 128 + cc]);
    }
    if (t < 128) {
        float A = g[t] * rsqrtf(v[t] + EPSV);
        c[t] = b2l[t] * A + (b[t] - m[t] * A) + bsk[t];
    }
}

__global__ void k_prep3(const float* __restrict__ W3l, const float* __restrict__ b3l,
                        const float* __restrict__ W3r, unsigned short* __restrict__ Wf,
                        float* __restrict__ c) {
    int t = blockIdx.x * 256 + threadIdx.x;  // K=128, NOUT=128 -> 2048 threads
    if (t >= 2048) return;
    int lane = t & 63, f = (t >> 6) & 3, kt = (t >> 8) & 3, nb = t >> 10;
    int col = nb * 64 + f * 16 + (lane & 15);
    int k0 = kt * 32 + (lane >> 4) * 8;
    unsigned short* o = Wf + (size_t)t * 8;
    if (col < 64) {
        for (int j = 0; j < 8; j++) o[j] = f2bf(W3l[(k0 + j) * 64 + col]);
    } else {
        int cc = col - 64;
        for (int j = 0; j < 8; j++) o[j] = f2bf(W3r[(k0 + j) * 64 + cc]);
    }
    if (t < 64) c[t] = b3l[t];
}

// ---------------- MFMA GEMM: Out[M][TOTN] = A[M][K] @ W (bf16, f32 acc)
// block: 4 waves, each wave 32 rows x 64 cols; grid (ceil(M/128), TOTN/64)
template <int K, int TOTN>
__global__ __launch_bounds__(256) void k_gemm(const unsigned short* __restrict__ A,
                                              const unsigned short* __restrict__ Wf,
                                              unsigned short* __restrict__ Out) {
    constexpr int KT = K / 32;
    __shared__ unsigned short Bs[K * 64];
    int tid = threadIdx.x;
    int bm = blockIdx.x, nb = blockIdx.y;

    // stage this n-block's B fragments (linear copy, K*128 bytes)
    {
        const float4* src = (const float4*)(Wf + (size_t)nb * K * 64);
        float4* dsts = (float4*)Bs;
        for (int i = tid; i < K * 8; i += 256) dsts[i] = src[i];
    }
    __syncthreads();

    int lane = tid & 63, w = tid >> 6;
    int r0 = bm * 128 + w * 32;
    int ra0 = r0 + (lane & 15);
    int ra1 = ra0 + 16;
    if (ra0 >= NN) ra0 = NN - 1;
    if (ra1 >= NN) ra1 = NN - 1;
    const unsigned short* ap0 = A + (size_t)ra0 * K + ((lane >> 4) * 8);
    const unsigned short* ap1 = A + (size_t)ra1 * K + ((lane >> 4) * 8);

    f32x4 acc[2][4];
#pragma unroll
    for (int i = 0; i < 2; i++)
#pragma unroll
        for (int j = 0; j < 4; j++) acc[i][j] = (f32x4){0.f, 0.f, 0.f, 0.f};

#pragma unroll
    for (int kt = 0; kt < KT; kt++) {
        short8 a0 = *(const short8*)(ap0 + kt * 32);
        short8 a1 = *(const short8*)(ap1 + kt * 32);
#pragma unroll
        for (int f = 0; f < 4; f++) {
            short8 bfr = *(const short8*)&Bs[((kt * 4 + f) * 64 + lane) * 8];
            acc[0][f] = __builtin_amdgcn_mfma_f32_16x16x32_bf16(a0, bfr, acc[0][f], 0, 0, 0);
            acc[1][f] = __builtin_amdgcn_mfma_f32_16x16x32_bf16(a1, bfr, acc[1][f], 0, 0, 0);
        }
    }

    // C/D layout: col = lane&15 (+f*16), row = (lane>>4)*4 + r (+af*16)
    int cc = nb * 64 + (lane & 15);
    int rb = r0 + (lane >> 4) * 4;
#pragma unroll
    for (int af = 0; af < 2; af++) {
#pragma unroll
        for (int f = 0; f < 4; f++) {
#pragma unroll
            for (int r = 0; r < 4; r++) {
                int gr = rb + af * 16 + r;
                if (gr < NN) Out[(size_t)gr * TOTN + cc + f * 16] = f2bf(acc[af][f][r]);
            }
        }
    }
}

// ---------------- fused aggregate: h = act(mean(gather P) + R + c)
// G layout: [NN][2D], P = cols 0..D-1, R = cols D..2D-1
template <int D, bool RELU>
__global__ void k_agg(const unsigned short* __restrict__ G, const int* __restrict__ rowptr,
                      const int* __restrict__ csr, const float* __restrict__ c,
                      unsigned short* __restrict__ out) {
    constexpr int VPL = D / 64;  // 4 (D=256) or 2 (D=128)
    int lane = threadIdx.x & 63, wv = threadIdx.x >> 6;
    int node = blockIdx.x * 4 + wv;
    if (node >= NN) return;
    int s0 = rowptr[node], s1 = rowptr[node + 1];
    float acc[VPL];
#pragma unroll
    for (int i = 0; i < VPL; i++) acc[i] = 0.f;

    const unsigned short* base = G + lane * VPL;
    for (int e = s0; e < s1; e++) {
        int s = csr[e];
        const unsigned short* p = base + (size_t)s * (2 * D);
        if constexpr (VPL == 4) {
            ushort4 u = *(const ushort4*)p;
            acc[0] += bf2f(u.x); acc[1] += bf2f(u.y);
            acc[2] += bf2f(u.z); acc[3] += bf2f(u.w);
        } else {
            ushort2 u = *(const ushort2*)p;
            acc[0] += bf2f(u.x); acc[1] += bf2f(u.y);
        }
    }
    float inv = 1.f / (float)max(s1 - s0, 1);
    const unsigned short* rrow = G + (size_t)node * (2 * D) + D + lane * VPL;
    unsigned short* o = out + (size_t)node * D + lane * VPL;
#pragma unroll
    for (int i = 0; i < VPL; i++) {
        float val = acc[i] * inv + bf2f(rrow[i]) + c[lane * VPL + i];
        if (RELU) val = fmaxf(val, 0.f);
        o[i] = f2bf(val);
    }
}

// ---------------- final: emb = mean(P) + R + c (f32), logits = emb @ Wc + bc (fused)
__global__ void k_agg_final(const unsigned short* __restrict__ G, const int* __restrict__ rowptr,
                            const int* __restrict__ csr, const float* __restrict__ c,
                            const float* __restrict__ Wc, const float* __restrict__ bc,
                            float* __restrict__ outbuf) {
    int lane = threadIdx.x & 63, wv = threadIdx.x >> 6;
    int node = blockIdx.x * 4 + wv;
    if (node >= NN) return;
    int s0 = rowptr[node], s1 = rowptr[node + 1];
    float acc = 0.f;
    const unsigned short* base = G + lane;
    for (int e = s0; e < s1; e++) acc += bf2f(base[(size_t)csr[e] * 128]);
    float val = acc / (float)max(s1 - s0, 1) + bf2f(G[(size_t)node * 128 + 64 + lane]) + c[lane];
    float* emb = outbuf + 2 * (size_t)NN;
    emb[(size_t)node * 64 + lane] = val;
    float l0 = val * Wc[2 * lane];
    float l1 = val * Wc[2 * lane + 1];
#pragma unroll
    for (int off = 32; off >= 1; off >>= 1) {
        l0 += __shfl_xor(l0, off);
        l1 += __shfl_xor(l1, off);
    }
    if (lane == 0) {
        outbuf[(size_t)node * 2 + 0] = l0 + bc[0];
        outbuf[(size_t)node * 2 + 1] = l1 + bc[1];
    }
}

extern "C" void kernel_launch(void* const* d_in, const int* in_sizes, int n_in,
                              void* d_out, int out_size, void* d_ws, size_t ws_size,
                              hipStream_t stream) {
    const float* x    = (const float*)d_in[0];
    const int*   ei   = (const int*)d_in[1];
    const float* Wp   = (const float*)d_in[2];
    const float* bp   = (const float*)d_in[3];
    const float* W1l  = (const float*)d_in[4];
    const float* b1l  = (const float*)d_in[5];
    const float* W1r  = (const float*)d_in[6];
    const float* bn1g = (const float*)d_in[7];
    const float* bn1b = (const float*)d_in[8];
    const float* bn1m = (const float*)d_in[9];
    const float* bn1v = (const float*)d_in[10];
    const float* Wsk  = (const float*)d_in[11];
    const float* bsk  = (const float*)d_in[12];
    const float* W2l  = (const float*)d_in[13];
    const float* b2l  = (const float*)d_in[14];
    const float* W2r  = (const float*)d_in[15];
    const float* bn2g = (const float*)d_in[16];
    const float* bn2b = (const float*)d_in[17];
    const float* bn2m = (const float*)d_in[18];
    const float* bn2v = (const float*)d_in[19];
    const float* W3l  = (const float*)d_in[20];
    const float* b3l  = (const float*)d_in[21];
    const float* W3r  = (const float*)d_in[22];
    const float* Wc   = (const float*)d_in[23];
    const float* bc   = (const float*)d_in[24];

    const int* src = ei;
    const int* dst = ei + NE;

    char* ws = (char*)d_ws;
    size_t o = 0;
    auto alloc = [&](size_t b) -> char* {
        char* p = ws + o;
        o = (o + b + 255) & ~(size_t)255;
        return p;
    };
    int* rowptr = (int*)alloc((NN + 1) * 4);
    int* pos    = (int*)alloc((size_t)NN * 4);
    int* csr    = (int*)alloc((size_t)NE * 4);
    unsigned short* xb = (unsigned short*)alloc((size_t)NN * 128 * 2);  // also reused as h2
    unsigned short* h1 = (unsigned short*)alloc((size_t)NN * 256 * 2);
    unsigned short* G  = (unsigned short*)alloc((size_t)NN * 512 * 2);  // g1, then g2, then g3
    unsigned short* Wf1 = (unsigned short*)alloc((size_t)512 * 128 * 2);
    unsigned short* Wf2 = (unsigned short*)alloc((size_t)256 * 256 * 2);
    unsigned short* Wf3 = (unsigned short*)alloc((size_t)128 * 128 * 2);
    float* c1 = (float*)alloc(256 * 4);
    float* c2 = (float*)alloc(128 * 4);
    float* c3 = (float*)alloc(64 * 4);
    unsigned short* h2 = xb;  // xb dead after GEMM1

    float* outbuf = (float*)d_out;  // logits [NN][2] then emb [NN][64]

    // CSR build
    hipMemsetAsync(pos, 0, (size_t)NN * 4, stream);
    k_count<<<3125, 256, 0, stream>>>(dst, pos);
    k_scan<<<1, 1024, 0, stream>>>(pos, rowptr);
    k_initpos<<<196, 256, 0, stream>>>(rowptr, pos);
    k_scatter<<<3125, 256, 0, stream>>>(src, dst, pos, csr);

    // prep
    k_xcast<<<6250, 256, 0, stream>>>(x, xb);
    k_prep1<<<32, 256, 0, stream>>>(Wp, bp, W1l, b1l, W1r, bn1g, bn1b, bn1m, bn1v, Wf1, c1);
    k_prep2<<<32, 256, 0, stream>>>(Wsk, bsk, W2l, b2l, W2r, bn2g, bn2b, bn2m, bn2v, Wf2, c2);
    k_prep3<<<8, 256, 0, stream>>>(W3l, b3l, W3r, Wf3, c3);

    // layer 1: [P1|R1] = xb @ Wf1 (K=128 -> 512 cols); h1 = relu(mean(P1)+R1+c1)
    k_gemm<128, 512><<<dim3(391, 8), 256, 0, stream>>>(xb, Wf1, G);
    k_agg<256, true><<<12500, 256, 0, stream>>>(G, rowptr, csr, c1, h1);

    // layer 2: [P2|R2] = h1 @ Wf2 (K=256 -> 256 cols); h2 = relu(mean(P2)+R2+c2)
    k_gemm<256, 256><<<dim3(391, 4), 256, 0, stream>>>(h1, Wf2, G);
    k_agg<128, true><<<12500, 256, 0, stream>>>(G, rowptr, csr, c2, h2);

    // layer 3: [P3|R3] = h2 @ Wf3 (K=128 -> 128 cols); emb = mean(P3)+R3+c3; logits fused
    k_gemm<128, 128><<<dim3(391, 2), 256, 0, stream>>>(h2, Wf3, G);
    k_agg_final<<<12500, 256, 0, stream>>>(G, rowptr, csr, c3, Wc, bc, outbuf);
}

// Round 3
// 320.524 us; speedup vs baseline: 2.2219x; 1.6034x over previous
//
#include <hip/hip_runtime.h>

#define NN 50000
#define NE 800000
constexpr float EPSV = 1e-5f;

typedef __attribute__((ext_vector_type(8))) short short8;
typedef __attribute__((ext_vector_type(4))) float f32x4;

__device__ __forceinline__ float bf2f(unsigned short u) {
    return __uint_as_float(((unsigned int)u) << 16);
}
__device__ __forceinline__ unsigned short f2bf(float f) {
    unsigned int x = __float_as_uint(f);
    return (unsigned short)((x + 0x7FFFu + ((x >> 16) & 1u)) >> 16);
}

// ---------------- CSR build ----------------
__global__ void k_count(const int* __restrict__ dst, int* __restrict__ deg) {
    int e = blockIdx.x * 256 + threadIdx.x;
    if (e < NE) atomicAdd(&deg[dst[e]], 1);
}

// parallel scan: per-block inclusive scan + block sums
__global__ void k_scan1(const int* __restrict__ deg, int* __restrict__ inc,
                        int* __restrict__ bsum) {
    __shared__ int buf[256];
    int tid = threadIdx.x;
    int i = blockIdx.x * 256 + tid;
    int v = (i < NN) ? deg[i] : 0;
    buf[tid] = v;
    __syncthreads();
    for (int off = 1; off < 256; off <<= 1) {
        int t = (tid >= off) ? buf[tid - off] : 0;
        __syncthreads();
        buf[tid] += t;
        __syncthreads();
    }
    if (i < NN) inc[i] = buf[tid];
    if (tid == 255) bsum[blockIdx.x] = buf[255];
}

__global__ void k_scan2(int* __restrict__ bsum) {  // exclusive scan of 196 block sums
    __shared__ int buf[256];
    int tid = threadIdx.x;
    int v = (tid < 196) ? bsum[tid] : 0;
    buf[tid] = v;
    __syncthreads();
    for (int off = 1; off < 256; off <<= 1) {
        int t = (tid >= off) ? buf[tid - off] : 0;
        __syncthreads();
        buf[tid] += t;
        __syncthreads();
    }
    if (tid < 196) bsum[tid] = buf[tid] - v;
}

__global__ void k_scan3(const int* __restrict__ inc, const int* __restrict__ deg,
                        const int* __restrict__ bsum, int* __restrict__ rowptr,
                        int* __restrict__ pos) {
    int i = blockIdx.x * 256 + threadIdx.x;
    if (i >= NN) return;
    int r = inc[i] + bsum[blockIdx.x];
    rowptr[i + 1] = r;
    pos[i] = r - deg[i];
    if (i == 0) rowptr[0] = 0;
}

__global__ void k_scatter(const int* __restrict__ src, const int* __restrict__ dst,
                          int* __restrict__ pos, int* __restrict__ csr) {
    int e = blockIdx.x * 256 + threadIdx.x;
    if (e < NE) {
        int p = atomicAdd(&pos[dst[e]], 1);
        csr[p] = src[e];
    }
}

// ---------------- x (f32) -> bf16 into xcat cols 128..255 ----------------
__global__ void k_xcast(const float* __restrict__ x, unsigned short* __restrict__ xcat) {
    int i = blockIdx.x * 256 + threadIdx.x;
    if (i >= NN * 128 / 4) return;
    int r = i >> 5, c4 = (i & 31) * 4;
    float4 v = ((const float4*)x)[i];
    ushort4 u = make_ushort4(f2bf(v.x), f2bf(v.y), f2bf(v.z), f2bf(v.w));
    *(ushort4*)&xcat[(size_t)r * 256 + 128 + c4] = u;
}

// ---------------- weight prep: fold BN+skip, bf16 MFMA B-fragment layout
// Wf layout: [nb][kt][f][lane][8j]; col = nb*64 + f*16 + (lane&15), k = kt*32 + (lane>>4)*8 + j
__global__ void k_prep1(const float* __restrict__ Wp, const float* __restrict__ bp,
                        const float* __restrict__ W1l, const float* __restrict__ b1l,
                        const float* __restrict__ W1r, const float* __restrict__ g,
                        const float* __restrict__ b, const float* __restrict__ m,
                        const float* __restrict__ v, unsigned short* __restrict__ Wf,
                        float* __restrict__ c) {
    int t = blockIdx.x * 256 + threadIdx.x;  // K=256, NOUT=256 -> 8192 threads
    if (t >= 8192) return;
    int lane = t & 63, f = (t >> 6) & 3, kt = (t >> 8) & 7, nb = t >> 11;
    int col = nb * 64 + f * 16 + (lane & 15);
    int k0 = kt * 32 + (lane >> 4) * 8;
    float A = g[col] * rsqrtf(v[col] + EPSV);
    unsigned short* o = Wf + (size_t)t * 8;
    for (int j = 0; j < 8; j++) {
        int k = k0 + j;
        float w;
        if (k < 128) w = W1l[k * 256 + col] * A;                                // mean block
        else         w = W1r[(k - 128) * 256 + col] * A + Wp[(k - 128) * 256 + col];  // root block
        o[j] = f2bf(w);
    }
    if (t < 256) {
        float At = g[t] * rsqrtf(v[t] + EPSV);
        c[t] = b1l[t] * At + (b[t] - m[t] * At) + bp[t];
    }
}

__global__ void k_prep2(const float* __restrict__ Wsk, const float* __restrict__ bsk,
                        const float* __restrict__ W2l, const float* __restrict__ b2l,
                        const float* __restrict__ W2r, const float* __restrict__ g,
                        const float* __restrict__ b, const float* __restrict__ m,
                        const float* __restrict__ v, unsigned short* __restrict__ Wf,
                        float* __restrict__ c) {
    int t = blockIdx.x * 256 + threadIdx.x;  // K=256, NOUT=256 -> 8192 threads
    if (t >= 8192) return;
    int lane = t & 63, f = (t >> 6) & 3, kt = (t >> 8) & 7, nb = t >> 11;
    int col = nb * 64 + f * 16 + (lane & 15);
    int k0 = kt * 32 + (lane >> 4) * 8;
    unsigned short* o = Wf + (size_t)t * 8;
    if (col < 128) {  // P2: W2l * A
        float A = g[col] * rsqrtf(v[col] + EPSV);
        for (int j = 0; j < 8; j++) o[j] = f2bf(W2l[(k0 + j) * 128 + col] * A);
    } else {          // R2: W2r * A + Wsk
        int cc = col - 128;
        float A = g[cc] * rsqrtf(v[cc] + EPSV);
        for (int j = 0; j < 8; j++)
            o[j] = f2bf(W2r[(k0 + j) * 128 + cc] * A + Wsk[(k0 + j) * 128 + cc]);
    }
    if (t < 128) {
        float At = g[t] * rsqrtf(v[t] + EPSV);
        c[t] = b2l[t] * At + (b[t] - m[t] * At) + bsk[t];
    }
}

__global__ void k_prep3(const float* __restrict__ W3l, const float* __restrict__ b3l,
                        const float* __restrict__ W3r, unsigned short* __restrict__ Wf,
                        float* __restrict__ c) {
    int t = blockIdx.x * 256 + threadIdx.x;  // K=128, NOUT=128 -> 2048 threads
    if (t >= 2048) return;
    int lane = t & 63, f = (t >> 6) & 3, kt = (t >> 8) & 3, nb = t >> 10;
    int col = nb * 64 + f * 16 + (lane & 15);
    int k0 = kt * 32 + (lane >> 4) * 8;
    unsigned short* o = Wf + (size_t)t * 8;
    if (col < 64) {
        for (int j = 0; j < 8; j++) o[j] = f2bf(W3l[(k0 + j) * 64 + col]);
    } else {
        int cc = col - 64;
        for (int j = 0; j < 8; j++) o[j] = f2bf(W3r[(k0 + j) * 64 + cc]);
    }
    if (t < 64) c[t] = b3l[t];
}

// ---------------- MFMA GEMM: Out[M][TOTN] = A[M][K] @ W ; optional bias+relu epilogue
template <int K, int TOTN, bool EPI>
__global__ __launch_bounds__(256) void k_gemm(const unsigned short* __restrict__ A,
                                              const unsigned short* __restrict__ Wf,
                                              const float* __restrict__ bias,
                                              unsigned short* __restrict__ Out) {
    constexpr int KT = K / 32;
    __shared__ unsigned short Bs[K * 64];
    int tid = threadIdx.x;
    int bm = blockIdx.x, nb = blockIdx.y;

    {
        const float4* srcp = (const float4*)(Wf + (size_t)nb * K * 64);
        float4* dsts = (float4*)Bs;
        for (int i = tid; i < K * 8; i += 256) dsts[i] = srcp[i];
    }
    __syncthreads();

    int lane = tid & 63, w = tid >> 6;
    int r0 = bm * 128 + w * 32;
    int ra0 = r0 + (lane & 15);
    int ra1 = ra0 + 16;
    if (ra0 >= NN) ra0 = NN - 1;
    if (ra1 >= NN) ra1 = NN - 1;
    const unsigned short* ap0 = A + (size_t)ra0 * K + ((lane >> 4) * 8);
    const unsigned short* ap1 = A + (size_t)ra1 * K + ((lane >> 4) * 8);

    f32x4 acc[2][4];
#pragma unroll
    for (int i = 0; i < 2; i++)
#pragma unroll
        for (int j = 0; j < 4; j++) acc[i][j] = (f32x4){0.f, 0.f, 0.f, 0.f};

#pragma unroll
    for (int kt = 0; kt < KT; kt++) {
        short8 a0 = *(const short8*)(ap0 + kt * 32);
        short8 a1 = *(const short8*)(ap1 + kt * 32);
#pragma unroll
        for (int f = 0; f < 4; f++) {
            short8 bfr = *(const short8*)&Bs[((kt * 4 + f) * 64 + lane) * 8];
            acc[0][f] = __builtin_amdgcn_mfma_f32_16x16x32_bf16(a0, bfr, acc[0][f], 0, 0, 0);
            acc[1][f] = __builtin_amdgcn_mfma_f32_16x16x32_bf16(a1, bfr, acc[1][f], 0, 0, 0);
        }
    }

    int cc = nb * 64 + (lane & 15);
    int rb = r0 + (lane >> 4) * 4;
#pragma unroll
    for (int af = 0; af < 2; af++) {
#pragma unroll
        for (int f = 0; f < 4; f++) {
            float bv = EPI ? bias[cc + f * 16] : 0.f;
#pragma unroll
            for (int r = 0; r < 4; r++) {
                int gr = rb + af * 16 + r;
                if (gr < NN) {
                    float val = acc[af][f][r];
                    if (EPI) val = fmaxf(val + bv, 0.f);
                    Out[(size_t)gr * TOTN + cc + f * 16] = f2bf(val);
                }
            }
        }
    }
}

// ---------------- layer-1 aggregate: mean of xb rows (cols 128..255 of xcat) -> cols 0..127
__global__ __launch_bounds__(256) void k_aggx(const int* __restrict__ rowptr,
                                              const int* __restrict__ csr,
                                              unsigned short* __restrict__ xcat) {
    int lane = threadIdx.x & 63, wv = threadIdx.x >> 6;
    int node = blockIdx.x * 4 + wv;
    if (node >= NN) return;
    int s0 = rowptr[node], s1 = rowptr[node + 1];
    int half = lane >> 5, l32 = lane & 31;
    float a0 = 0.f, a1 = 0.f, a2 = 0.f, a3 = 0.f;
    const unsigned short* base = xcat + 128 + l32 * 4;
    int e = s0;
    for (; e + 2 <= s1; e += 2) {
        int s = csr[e + half];
        ushort4 u = *(const ushort4*)(base + (size_t)s * 256);
        a0 += bf2f(u.x); a1 += bf2f(u.y); a2 += bf2f(u.z); a3 += bf2f(u.w);
    }
    if (e < s1 && half == 0) {
        int s = csr[e];
        ushort4 u = *(const ushort4*)(base + (size_t)s * 256);
        a0 += bf2f(u.x); a1 += bf2f(u.y); a2 += bf2f(u.z); a3 += bf2f(u.w);
    }
    a0 += __shfl_xor(a0, 32); a1 += __shfl_xor(a1, 32);
    a2 += __shfl_xor(a2, 32); a3 += __shfl_xor(a3, 32);
    if (half == 0) {
        float inv = 1.f / (float)max(s1 - s0, 1);
        ushort4 u = make_ushort4(f2bf(a0 * inv), f2bf(a1 * inv), f2bf(a2 * inv), f2bf(a3 * inv));
        *(ushort4*)&xcat[(size_t)node * 256 + l32 * 4] = u;
    }
}

// ---------------- layer-2 aggregate: h2 = relu(mean(gather P2) + R2 + c2)
// G layout [NN][256]: P2 = cols 0..127, R2 = cols 128..255
__global__ __launch_bounds__(256) void k_agg2(const unsigned short* __restrict__ G,
                                              const int* __restrict__ rowptr,
                                              const int* __restrict__ csr,
                                              const float* __restrict__ c,
                                              unsigned short* __restrict__ h2) {
    int lane = threadIdx.x & 63, wv = threadIdx.x >> 6;
    int node = blockIdx.x * 4 + wv;
    if (node >= NN) return;
    int s0 = rowptr[node], s1 = rowptr[node + 1];
    int half = lane >> 5, l32 = lane & 31;
    float a0 = 0.f, a1 = 0.f, a2 = 0.f, a3 = 0.f;
    const unsigned short* base = G + l32 * 4;
    int e = s0;
    for (; e + 2 <= s1; e += 2) {
        int s = csr[e + half];
        ushort4 u = *(const ushort4*)(base + (size_t)s * 256);
        a0 += bf2f(u.x); a1 += bf2f(u.y); a2 += bf2f(u.z); a3 += bf2f(u.w);
    }
    if (e < s1 && half == 0) {
        int s = csr[e];
        ushort4 u = *(const ushort4*)(base + (size_t)s * 256);
        a0 += bf2f(u.x); a1 += bf2f(u.y); a2 += bf2f(u.z); a3 += bf2f(u.w);
    }
    a0 += __shfl_xor(a0, 32); a1 += __shfl_xor(a1, 32);
    a2 += __shfl_xor(a2, 32); a3 += __shfl_xor(a3, 32);
    if (half == 0) {
        float inv = 1.f / (float)max(s1 - s0, 1);
        ushort4 r = *(const ushort4*)&G[(size_t)node * 256 + 128 + l32 * 4];
        const float* cp = c + l32 * 4;
        float v0 = fmaxf(a0 * inv + bf2f(r.x) + cp[0], 0.f);
        float v1 = fmaxf(a1 * inv + bf2f(r.y) + cp[1], 0.f);
        float v2 = fmaxf(a2 * inv + bf2f(r.z) + cp[2], 0.f);
        float v3 = fmaxf(a3 * inv + bf2f(r.w) + cp[3], 0.f);
        *(ushort4*)&h2[(size_t)node * 128 + l32 * 4] = make_ushort4(f2bf(v0), f2bf(v1), f2bf(v2), f2bf(v3));
    }
}

// ---------------- final: emb = mean(gather P3) + R3 + c3 (f32); logits fused
// G layout [NN][128]: P3 = cols 0..63, R3 = cols 64..127
__global__ __launch_bounds__(256) void k_agg_final(const unsigned short* __restrict__ G,
                                                   const int* __restrict__ rowptr,
                                                   const int* __restrict__ csr,
                                                   const float* __restrict__ c,
                                                   const float* __restrict__ Wc,
                                                   const float* __restrict__ bc,
                                                   float* __restrict__ outbuf) {
    int lane = threadIdx.x & 63, wv = threadIdx.x >> 6;
    int node = blockIdx.x * 4 + wv;
    if (node >= NN) return;
    int s0 = rowptr[node], s1 = rowptr[node + 1];
    int q = lane >> 4, l16 = lane & 15;
    float a0 = 0.f, a1 = 0.f, a2 = 0.f, a3 = 0.f;
    const unsigned short* base = G + l16 * 4;
    int e = s0;
    for (; e + 4 <= s1; e += 4) {
        int s = csr[e + q];
        ushort4 u = *(const ushort4*)(base + (size_t)s * 128);
        a0 += bf2f(u.x); a1 += bf2f(u.y); a2 += bf2f(u.z); a3 += bf2f(u.w);
    }
    if (e + q < s1) {
        int s = csr[e + q];
        ushort4 u = *(const ushort4*)(base + (size_t)s * 128);
        a0 += bf2f(u.x); a1 += bf2f(u.y); a2 += bf2f(u.z); a3 += bf2f(u.w);
    }
    a0 += __shfl_xor(a0, 16); a1 += __shfl_xor(a1, 16);
    a2 += __shfl_xor(a2, 16); a3 += __shfl_xor(a3, 16);
    a0 += __shfl_xor(a0, 32); a1 += __shfl_xor(a1, 32);
    a2 += __shfl_xor(a2, 32); a3 += __shfl_xor(a3, 32);

    float l0 = 0.f, l1 = 0.f;
    if (q == 0) {
        float inv = 1.f / (float)max(s1 - s0, 1);
        ushort4 r = *(const ushort4*)&G[(size_t)node * 128 + 64 + l16 * 4];
        const float* cp = c + l16 * 4;
        float v0 = a0 * inv + bf2f(r.x) + cp[0];
        float v1 = a1 * inv + bf2f(r.y) + cp[1];
        float v2 = a2 * inv + bf2f(r.z) + cp[2];
        float v3 = a3 * inv + bf2f(r.w) + cp[3];
        float* emb = outbuf + 2 * (size_t)NN;
        *(float4*)&emb[(size_t)node * 64 + l16 * 4] = make_float4(v0, v1, v2, v3);
        int c0 = l16 * 4;
        l0 = v0 * Wc[2 * c0] + v1 * Wc[2 * (c0 + 1)] + v2 * Wc[2 * (c0 + 2)] + v3 * Wc[2 * (c0 + 3)];
        l1 = v0 * Wc[2 * c0 + 1] + v1 * Wc[2 * (c0 + 1) + 1] + v2 * Wc[2 * (c0 + 2) + 1] + v3 * Wc[2 * (c0 + 3) + 1];
    }
    l0 += __shfl_xor(l0, 8); l1 += __shfl_xor(l1, 8);
    l0 += __shfl_xor(l0, 4); l1 += __shfl_xor(l1, 4);
    l0 += __shfl_xor(l0, 2); l1 += __shfl_xor(l1, 2);
    l0 += __shfl_xor(l0, 1); l1 += __shfl_xor(l1, 1);
    if (lane == 0) {
        outbuf[(size_t)node * 2 + 0] = l0 + bc[0];
        outbuf[(size_t)node * 2 + 1] = l1 + bc[1];
    }
}

extern "C" void kernel_launch(void* const* d_in, const int* in_sizes, int n_in,
                              void* d_out, int out_size, void* d_ws, size_t ws_size,
                              hipStream_t stream) {
    const float* x    = (const float*)d_in[0];
    const int*   ei   = (const int*)d_in[1];
    const float* Wp   = (const float*)d_in[2];
    const float* bp   = (const float*)d_in[3];
    const float* W1l  = (const float*)d_in[4];
    const float* b1l  = (const float*)d_in[5];
    const float* W1r  = (const float*)d_in[6];
    const float* bn1g = (const float*)d_in[7];
    const float* bn1b = (const float*)d_in[8];
    const float* bn1m = (const float*)d_in[9];
    const float* bn1v = (const float*)d_in[10];
    const float* Wsk  = (const float*)d_in[11];
    const float* bsk  = (const float*)d_in[12];
    const float* W2l  = (const float*)d_in[13];
    const float* b2l  = (const float*)d_in[14];
    const float* W2r  = (const float*)d_in[15];
    const float* bn2g = (const float*)d_in[16];
    const float* bn2b = (const float*)d_in[17];
    const float* bn2m = (const float*)d_in[18];
    const float* bn2v = (const float*)d_in[19];
    const float* W3l  = (const float*)d_in[20];
    const float* b3l  = (const float*)d_in[21];
    const float* W3r  = (const float*)d_in[22];
    const float* Wc   = (const float*)d_in[23];
    const float* bc   = (const float*)d_in[24];

    const int* src = ei;
    const int* dst = ei + NE;

    char* ws = (char*)d_ws;
    size_t o = 0;
    auto alloc = [&](size_t b) -> char* {
        char* p = ws + o;
        o = (o + b + 255) & ~(size_t)255;
        return p;
    };
    int* deg    = (int*)alloc((size_t)NN * 4);
    int* inc    = (int*)alloc((size_t)NN * 4);
    int* bsum   = (int*)alloc(256 * 4);
    int* rowptr = (int*)alloc((NN + 1) * 4);
    int* pos    = (int*)alloc((size_t)NN * 4);
    int* csr    = (int*)alloc((size_t)NE * 4);
    unsigned short* xcat = (unsigned short*)alloc((size_t)NN * 256 * 2);  // [mean1|xb]
    unsigned short* h1   = (unsigned short*)alloc((size_t)NN * 256 * 2);
    unsigned short* h2   = (unsigned short*)alloc((size_t)NN * 128 * 2);
    unsigned short* G    = (unsigned short*)alloc((size_t)NN * 256 * 2);  // [P|R] per layer
    unsigned short* Wf1  = (unsigned short*)alloc((size_t)256 * 256 * 2);
    unsigned short* Wf2  = (unsigned short*)alloc((size_t)256 * 256 * 2);
    unsigned short* Wf3  = (unsigned short*)alloc((size_t)128 * 128 * 2);
    float* c1 = (float*)alloc(256 * 4);
    float* c2 = (float*)alloc(128 * 4);
    float* c3 = (float*)alloc(64 * 4);

    float* outbuf = (float*)d_out;  // logits [NN][2] then emb [NN][64]

    // CSR build
    hipMemsetAsync(deg, 0, (size_t)NN * 4, stream);
    k_count<<<3125, 256, 0, stream>>>(dst, deg);
    k_scan1<<<196, 256, 0, stream>>>(deg, inc, bsum);
    k_scan2<<<1, 256, 0, stream>>>(bsum);
    k_scan3<<<196, 256, 0, stream>>>(inc, deg, bsum, rowptr, pos);
    k_scatter<<<3125, 256, 0, stream>>>(src, dst, pos, csr);

    // prep
    k_xcast<<<6250, 256, 0, stream>>>(x, xcat);
    k_prep1<<<32, 256, 0, stream>>>(Wp, bp, W1l, b1l, W1r, bn1g, bn1b, bn1m, bn1v, Wf1, c1);
    k_prep2<<<32, 256, 0, stream>>>(Wsk, bsk, W2l, b2l, W2r, bn2g, bn2b, bn2m, bn2v, Wf2, c2);
    k_prep3<<<8, 256, 0, stream>>>(W3l, b3l, W3r, Wf3, c3);

    // layer 1: mean(xb) into xcat cols 0..127; h1 = relu([mean|xb] @ Wf1 + c1)
    k_aggx<<<12500, 256, 0, stream>>>(rowptr, csr, xcat);
    k_gemm<256, 256, true><<<dim3(391, 4), 256, 0, stream>>>(xcat, Wf1, c1, h1);

    // layer 2: [P2|R2] = h1 @ Wf2 ; h2 = relu(mean(P2) + R2 + c2)
    k_gemm<256, 256, false><<<dim3(391, 4), 256, 0, stream>>>(h1, Wf2, nullptr, G);
    k_agg2<<<12500, 256, 0, stream>>>(G, rowptr, csr, c2, h2);

    // layer 3: [P3|R3] = h2 @ Wf3 ; emb = mean(P3)+R3+c3 ; logits fused
    k_gemm<128, 128, false><<<dim3(391, 2), 256, 0, stream>>>(h2, Wf3, nullptr, G);
    k_agg_final<<<12500, 256, 0, stream>>>(G, rowptr, csr, c3, Wc, bc, outbuf);
}

// Round 4
// 277.712 us; speedup vs baseline: 2.5644x; 1.1542x over previous
//
#include <hip/hip_runtime.h>

#define NN 50000
#define NE 800000
#define SLN 6250  // NN/8 nodes per XCD slice
constexpr float EPSV = 1e-5f;

typedef __attribute__((ext_vector_type(8))) short short8;
typedef __attribute__((ext_vector_type(4))) float f32x4;

__device__ __forceinline__ float bf2f(unsigned short u) {
    return __uint_as_float(((unsigned int)u) << 16);
}
__device__ __forceinline__ unsigned short f2bf(float f) {
    unsigned int x = __float_as_uint(f);
    return (unsigned short)((x + 0x7FFFu + ((x >> 16) & 1u)) >> 16);
}

// ---------------- CSR build (XCD-sliced: block b owns node slice b&7) ----------------
__global__ __launch_bounds__(256) void k_count(const int* __restrict__ dst, int* __restrict__ deg) {
    int lo = (blockIdx.x & 7) * SLN;
    int lb = blockIdx.x >> 3;  // 0..127
    const int4* d4 = (const int4*)dst;
    constexpr int NQ = NE / 4;
    for (int q = lb * 256 + threadIdx.x; q < NQ; q += 128 * 256) {
        int4 d = d4[q];
        if ((unsigned)(d.x - lo) < SLN) atomicAdd(&deg[d.x], 1);
        if ((unsigned)(d.y - lo) < SLN) atomicAdd(&deg[d.y], 1);
        if ((unsigned)(d.z - lo) < SLN) atomicAdd(&deg[d.z], 1);
        if ((unsigned)(d.w - lo) < SLN) atomicAdd(&deg[d.w], 1);
    }
}

__global__ __launch_bounds__(256) void k_scatter(const int* __restrict__ src,
                                                 const int* __restrict__ dst,
                                                 int* __restrict__ pos, int* __restrict__ csr) {
    int lo = (blockIdx.x & 7) * SLN;
    int lb = blockIdx.x >> 3;
    const int4* d4 = (const int4*)dst;
    const int4* s4 = (const int4*)src;
    constexpr int NQ = NE / 4;
    for (int q = lb * 256 + threadIdx.x; q < NQ; q += 128 * 256) {
        int4 d = d4[q];
        int4 s = s4[q];
        if ((unsigned)(d.x - lo) < SLN) csr[atomicAdd(&pos[d.x], 1)] = s.x;
        if ((unsigned)(d.y - lo) < SLN) csr[atomicAdd(&pos[d.y], 1)] = s.y;
        if ((unsigned)(d.z - lo) < SLN) csr[atomicAdd(&pos[d.z], 1)] = s.z;
        if ((unsigned)(d.w - lo) < SLN) csr[atomicAdd(&pos[d.w], 1)] = s.w;
    }
}

// parallel scan: per-block inclusive scan + block sums
__global__ void k_scan1(const int* __restrict__ deg, int* __restrict__ inc,
                        int* __restrict__ bsum) {
    __shared__ int buf[256];
    int tid = threadIdx.x;
    int i = blockIdx.x * 256 + tid;
    int v = (i < NN) ? deg[i] : 0;
    buf[tid] = v;
    __syncthreads();
    for (int off = 1; off < 256; off <<= 1) {
        int t = (tid >= off) ? buf[tid - off] : 0;
        __syncthreads();
        buf[tid] += t;
        __syncthreads();
    }
    if (i < NN) inc[i] = buf[tid];
    if (tid == 255) bsum[blockIdx.x] = buf[255];
}

__global__ void k_scan2(int* __restrict__ bsum) {  // exclusive scan of 196 block sums
    __shared__ int buf[256];
    int tid = threadIdx.x;
    int v = (tid < 196) ? bsum[tid] : 0;
    buf[tid] = v;
    __syncthreads();
    for (int off = 1; off < 256; off <<= 1) {
        int t = (tid >= off) ? buf[tid - off] : 0;
        __syncthreads();
        buf[tid] += t;
        __syncthreads();
    }
    if (tid < 196) bsum[tid] = buf[tid] - v;
}

__global__ void k_scan3(const int* __restrict__ inc, const int* __restrict__ deg,
                        const int* __restrict__ bsum, int* __restrict__ rowptr,
                        int* __restrict__ pos) {
    int i = blockIdx.x * 256 + threadIdx.x;
    if (i >= NN) return;
    int r = inc[i] + bsum[blockIdx.x];
    rowptr[i + 1] = r;
    pos[i] = r - deg[i];
    if (i == 0) rowptr[0] = 0;
}

// ---------------- x (f32) -> bf16 into xcat cols 128..255 ; also zeroes deg ----------------
__global__ void k_xcast(const float* __restrict__ x, unsigned short* __restrict__ xcat,
                        int* __restrict__ deg) {
    int i = blockIdx.x * 256 + threadIdx.x;
    if (i < NN / 4) ((int4*)deg)[i] = make_int4(0, 0, 0, 0);
    if (i >= NN * 128 / 4) return;
    int r = i >> 5, c4 = (i & 31) * 4;
    float4 v = ((const float4*)x)[i];
    ushort4 u = make_ushort4(f2bf(v.x), f2bf(v.y), f2bf(v.z), f2bf(v.w));
    *(ushort4*)&xcat[(size_t)r * 256 + 128 + c4] = u;
}

// ---------------- fused weight prep: fold BN+skip, bf16 MFMA B-fragment layout
// Wf layout: [nb][kt][f][lane][8j]; col = nb*64 + f*16 + (lane&15), k = kt*32 + (lane>>4)*8 + j
__device__ void prep1_body(int t, const float* Wp, const float* bp, const float* W1l,
                           const float* b1l, const float* W1r, const float* g, const float* b,
                           const float* m, const float* v, unsigned short* Wf, float* c) {
    int lane = t & 63, f = (t >> 6) & 3, kt = (t >> 8) & 7;
    int nb = t >> 11;
    int col = nb * 64 + f * 16 + (lane & 15);
    int k0 = kt * 32 + (lane >> 4) * 8;
    float A = g[col] * rsqrtf(v[col] + EPSV);
    unsigned short* o = Wf + (size_t)t * 8;
    for (int j = 0; j < 8; j++) {
        int k = k0 + j;
        float w;
        if (k < 128) w = W1l[k * 256 + col] * A;
        else         w = W1r[(k - 128) * 256 + col] * A + Wp[(k - 128) * 256 + col];
        o[j] = f2bf(w);
    }
    if (t < 256) {
        float At = g[t] * rsqrtf(v[t] + EPSV);
        c[t] = b1l[t] * At + (b[t] - m[t] * At) + bp[t];
    }
}

__device__ void prep2_body(int t, const float* Wsk, const float* bsk, const float* W2l,
                           const float* b2l, const float* W2r, const float* g, const float* b,
                           const float* m, const float* v, unsigned short* Wf, float* c) {
    int lane = t & 63, f = (t >> 6) & 3, kt = (t >> 8) & 7, nb = t >> 11;
    int col = nb * 64 + f * 16 + (lane & 15);
    int k0 = kt * 32 + (lane >> 4) * 8;
    unsigned short* o = Wf + (size_t)t * 8;
    if (col < 128) {
        float A = g[col] * rsqrtf(v[col] + EPSV);
        for (int j = 0; j < 8; j++) o[j] = f2bf(W2l[(k0 + j) * 128 + col] * A);
    } else {
        int cc = col - 128;
        float A = g[cc] * rsqrtf(v[cc] + EPSV);
        for (int j = 0; j < 8; j++)
            o[j] = f2bf(W2r[(k0 + j) * 128 + cc] * A + Wsk[(k0 + j) * 128 + cc]);
    }
    if (t < 128) {
        float At = g[t] * rsqrtf(v[t] + EPSV);
        c[t] = b2l[t] * At + (b[t] - m[t] * At) + bsk[t];
    }
}

__device__ void prep3_body(int t, const float* W3l, const float* b3l, const float* W3r,
                           unsigned short* Wf, float* c) {
    int lane = t & 63, f = (t >> 6) & 3, kt = (t >> 8) & 3, nb = t >> 10;
    int col = nb * 64 + f * 16 + (lane & 15);
    int k0 = kt * 32 + (lane >> 4) * 8;
    unsigned short* o = Wf + (size_t)t * 8;
    if (col < 64) {
        for (int j = 0; j < 8; j++) o[j] = f2bf(W3l[(k0 + j) * 64 + col]);
    } else {
        int cc = col - 64;
        for (int j = 0; j < 8; j++) o[j] = f2bf(W3r[(k0 + j) * 64 + cc]);
    }
    if (t < 64) c[t] = b3l[t];
}

__global__ void k_prep_all(const float* Wp, const float* bp,
                           const float* W1l, const float* b1l, const float* W1r,
                           const float* g1, const float* b1, const float* m1, const float* v1,
                           const float* Wsk, const float* bsk,
                           const float* W2l, const float* b2l, const float* W2r,
                           const float* g2, const float* b2, const float* m2, const float* v2,
                           const float* W3l, const float* b3l, const float* W3r,
                           unsigned short* Wf1, unsigned short* Wf2, unsigned short* Wf3,
                           float* c1, float* c2, float* c3) {
    int bb = blockIdx.x;
    if (bb < 32) {
        prep1_body(bb * 256 + threadIdx.x, Wp, bp, W1l, b1l, W1r, g1, b1, m1, v1, Wf1, c1);
    } else if (bb < 64) {
        prep2_body((bb - 32) * 256 + threadIdx.x, Wsk, bsk, W2l, b2l, W2r, g2, b2, m2, v2, Wf2, c2);
    } else {
        prep3_body((bb - 64) * 256 + threadIdx.x, W3l, b3l, W3r, Wf3, c3);
    }
}

// ---------------- MFMA GEMM: Out[M][TOTN] = A[M][K] @ W ; optional bias+relu epilogue
template <int K, int TOTN, bool EPI>
__global__ __launch_bounds__(256) void k_gemm(const unsigned short* __restrict__ A,
                                              const unsigned short* __restrict__ Wf,
                                              const float* __restrict__ bias,
                                              unsigned short* __restrict__ Out) {
    constexpr int KT = K / 32;
    __shared__ unsigned short Bs[K * 64];
    int tid = threadIdx.x;
    int bm = blockIdx.x, nb = blockIdx.y;

    {
        const float4* srcp = (const float4*)(Wf + (size_t)nb * K * 64);
        float4* dsts = (float4*)Bs;
        for (int i = tid; i < K * 8; i += 256) dsts[i] = srcp[i];
    }
    __syncthreads();

    int lane = tid & 63, w = tid >> 6;
    int r0 = bm * 128 + w * 32;
    int ra0 = r0 + (lane & 15);
    int ra1 = ra0 + 16;
    if (ra0 >= NN) ra0 = NN - 1;
    if (ra1 >= NN) ra1 = NN - 1;
    const unsigned short* ap0 = A + (size_t)ra0 * K + ((lane >> 4) * 8);
    const unsigned short* ap1 = A + (size_t)ra1 * K + ((lane >> 4) * 8);

    f32x4 acc[2][4];
#pragma unroll
    for (int i = 0; i < 2; i++)
#pragma unroll
        for (int j = 0; j < 4; j++) acc[i][j] = (f32x4){0.f, 0.f, 0.f, 0.f};

#pragma unroll
    for (int kt = 0; kt < KT; kt++) {
        short8 a0 = *(const short8*)(ap0 + kt * 32);
        short8 a1 = *(const short8*)(ap1 + kt * 32);
#pragma unroll
        for (int f = 0; f < 4; f++) {
            short8 bfr = *(const short8*)&Bs[((kt * 4 + f) * 64 + lane) * 8];
            acc[0][f] = __builtin_amdgcn_mfma_f32_16x16x32_bf16(a0, bfr, acc[0][f], 0, 0, 0);
            acc[1][f] = __builtin_amdgcn_mfma_f32_16x16x32_bf16(a1, bfr, acc[1][f], 0, 0, 0);
        }
    }

    int cc = nb * 64 + (lane & 15);
    int rb = r0 + (lane >> 4) * 4;
#pragma unroll
    for (int af = 0; af < 2; af++) {
#pragma unroll
        for (int f = 0; f < 4; f++) {
            float bv = EPI ? bias[cc + f * 16] : 0.f;
#pragma unroll
            for (int r = 0; r < 4; r++) {
                int gr = rb + af * 16 + r;
                if (gr < NN) {
                    float val = acc[af][f][r];
                    if (EPI) val = fmaxf(val + bv, 0.f);
                    Out[(size_t)gr * TOTN + cc + f * 16] = f2bf(val);
                }
            }
        }
    }
}

// ---------------- layer-1 aggregate: mean of xb rows (cols 128..255 of xcat) -> cols 0..127
__global__ __launch_bounds__(256) void k_aggx(const int* __restrict__ rowptr,
                                              const int* __restrict__ csr,
                                              unsigned short* __restrict__ xcat) {
    int lane = threadIdx.x & 63, wv = threadIdx.x >> 6;
    int node = blockIdx.x * 4 + wv;
    if (node >= NN) return;
    int s0 = rowptr[node], s1 = rowptr[node + 1];
    int half = lane >> 5, l32 = lane & 31;
    float a0 = 0.f, a1 = 0.f, a2 = 0.f, a3 = 0.f;
    const unsigned short* base = xcat + 128 + l32 * 4;
    int e = s0;
    for (; e + 4 <= s1; e += 4) {
        int sA = csr[e + half], sB = csr[e + 2 + half];
        ushort4 uA = *(const ushort4*)(base + (size_t)sA * 256);
        ushort4 uB = *(const ushort4*)(base + (size_t)sB * 256);
        a0 += bf2f(uA.x) + bf2f(uB.x); a1 += bf2f(uA.y) + bf2f(uB.y);
        a2 += bf2f(uA.z) + bf2f(uB.z); a3 += bf2f(uA.w) + bf2f(uB.w);
    }
    if (e + 2 <= s1) {
        int s = csr[e + half];
        ushort4 u = *(const ushort4*)(base + (size_t)s * 256);
        a0 += bf2f(u.x); a1 += bf2f(u.y); a2 += bf2f(u.z); a3 += bf2f(u.w);
        e += 2;
    }
    if (e < s1 && half == 0) {
        int s = csr[e];
        ushort4 u = *(const ushort4*)(base + (size_t)s * 256);
        a0 += bf2f(u.x); a1 += bf2f(u.y); a2 += bf2f(u.z); a3 += bf2f(u.w);
    }
    a0 += __shfl_xor(a0, 32); a1 += __shfl_xor(a1, 32);
    a2 += __shfl_xor(a2, 32); a3 += __shfl_xor(a3, 32);
    if (half == 0) {
        float inv = 1.f / (float)max(s1 - s0, 1);
        ushort4 u = make_ushort4(f2bf(a0 * inv), f2bf(a1 * inv), f2bf(a2 * inv), f2bf(a3 * inv));
        *(ushort4*)&xcat[(size_t)node * 256 + l32 * 4] = u;
    }
}

// ---------------- layer-2 aggregate: h2 = relu(mean(gather P2) + R2 + c2)
// G layout [NN][256]: P2 = cols 0..127, R2 = cols 128..255
__global__ __launch_bounds__(256) void k_agg2(const unsigned short* __restrict__ G,
                                              const int* __restrict__ rowptr,
                                              const int* __restrict__ csr,
                                              const float* __restrict__ c,
                                              unsigned short* __restrict__ h2) {
    int lane = threadIdx.x & 63, wv = threadIdx.x >> 6;
    int node = blockIdx.x * 4 + wv;
    if (node >= NN) return;
    int s0 = rowptr[node], s1 = rowptr[node + 1];
    int half = lane >> 5, l32 = lane & 31;
    float a0 = 0.f, a1 = 0.f, a2 = 0.f, a3 = 0.f;
    const unsigned short* base = G + l32 * 4;
    int e = s0;
    for (; e + 4 <= s1; e += 4) {
        int sA = csr[e + half], sB = csr[e + 2 + half];
        ushort4 uA = *(const ushort4*)(base + (size_t)sA * 256);
        ushort4 uB = *(const ushort4*)(base + (size_t)sB * 256);
        a0 += bf2f(uA.x) + bf2f(uB.x); a1 += bf2f(uA.y) + bf2f(uB.y);
        a2 += bf2f(uA.z) + bf2f(uB.z); a3 += bf2f(uA.w) + bf2f(uB.w);
    }
    if (e + 2 <= s1) {
        int s = csr[e + half];
        ushort4 u = *(const ushort4*)(base + (size_t)s * 256);
        a0 += bf2f(u.x); a1 += bf2f(u.y); a2 += bf2f(u.z); a3 += bf2f(u.w);
        e += 2;
    }
    if (e < s1 && half == 0) {
        int s = csr[e];
        ushort4 u = *(const ushort4*)(base + (size_t)s * 256);
        a0 += bf2f(u.x); a1 += bf2f(u.y); a2 += bf2f(u.z); a3 += bf2f(u.w);
    }
    a0 += __shfl_xor(a0, 32); a1 += __shfl_xor(a1, 32);
    a2 += __shfl_xor(a2, 32); a3 += __shfl_xor(a3, 32);
    if (half == 0) {
        float inv = 1.f / (float)max(s1 - s0, 1);
        ushort4 r = *(const ushort4*)&G[(size_t)node * 256 + 128 + l32 * 4];
        const float* cp = c + l32 * 4;
        float v0 = fmaxf(a0 * inv + bf2f(r.x) + cp[0], 0.f);
        float v1 = fmaxf(a1 * inv + bf2f(r.y) + cp[1], 0.f);
        float v2 = fmaxf(a2 * inv + bf2f(r.z) + cp[2], 0.f);
        float v3 = fmaxf(a3 * inv + bf2f(r.w) + cp[3], 0.f);
        *(ushort4*)&h2[(size_t)node * 128 + l32 * 4] = make_ushort4(f2bf(v0), f2bf(v1), f2bf(v2), f2bf(v3));
    }
}

// ---------------- final: emb = mean(gather P3) + R3 + c3 (f32); logits fused
// G layout [NN][128]: P3 = cols 0..63, R3 = cols 64..127
__global__ __launch_bounds__(256) void k_agg_final(const unsigned short* __restrict__ G,
                                                   const int* __restrict__ rowptr,
                                                   const int* __restrict__ csr,
                                                   const float* __restrict__ c,
                                                   const float* __restrict__ Wc,
                                                   const float* __restrict__ bc,
                                                   float* __restrict__ outbuf) {
    int lane = threadIdx.x & 63, wv = threadIdx.x >> 6;
    int node = blockIdx.x * 4 + wv;
    if (node >= NN) return;
    int s0 = rowptr[node], s1 = rowptr[node + 1];
    int q = lane >> 4, l16 = lane & 15;
    float a0 = 0.f, a1 = 0.f, a2 = 0.f, a3 = 0.f;
    const unsigned short* base = G + l16 * 4;
    int e = s0;
    for (; e + 8 <= s1; e += 8) {
        int sA = csr[e + q], sB = csr[e + 4 + q];
        ushort4 uA = *(const ushort4*)(base + (size_t)sA * 128);
        ushort4 uB = *(const ushort4*)(base + (size_t)sB * 128);
        a0 += bf2f(uA.x) + bf2f(uB.x); a1 += bf2f(uA.y) + bf2f(uB.y);
        a2 += bf2f(uA.z) + bf2f(uB.z); a3 += bf2f(uA.w) + bf2f(uB.w);
    }
    if (e + 4 <= s1) {
        int s = csr[e + q];
        ushort4 u = *(const ushort4*)(base + (size_t)s * 128);
        a0 += bf2f(u.x); a1 += bf2f(u.y); a2 += bf2f(u.z); a3 += bf2f(u.w);
        e += 4;
    }
    if (e + q < s1) {
        int s = csr[e + q];
        ushort4 u = *(const ushort4*)(base + (size_t)s * 128);
        a0 += bf2f(u.x); a1 += bf2f(u.y); a2 += bf2f(u.z); a3 += bf2f(u.w);
    }
    a0 += __shfl_xor(a0, 16); a1 += __shfl_xor(a1, 16);
    a2 += __shfl_xor(a2, 16); a3 += __shfl_xor(a3, 16);
    a0 += __shfl_xor(a0, 32); a1 += __shfl_xor(a1, 32);
    a2 += __shfl_xor(a2, 32); a3 += __shfl_xor(a3, 32);

    float l0 = 0.f, l1 = 0.f;
    if (q == 0) {
        float inv = 1.f / (float)max(s1 - s0, 1);
        ushort4 r = *(const ushort4*)&G[(size_t)node * 128 + 64 + l16 * 4];
        const float* cp = c + l16 * 4;
        float v0 = a0 * inv + bf2f(r.x) + cp[0];
        float v1 = a1 * inv + bf2f(r.y) + cp[1];
        float v2 = a2 * inv + bf2f(r.z) + cp[2];
        float v3 = a3 * inv + bf2f(r.w) + cp[3];
        float* emb = outbuf + 2 * (size_t)NN;
        *(float4*)&emb[(size_t)node * 64 + l16 * 4] = make_float4(v0, v1, v2, v3);
        int c0 = l16 * 4;
        l0 = v0 * Wc[2 * c0] + v1 * Wc[2 * (c0 + 1)] + v2 * Wc[2 * (c0 + 2)] + v3 * Wc[2 * (c0 + 3)];
        l1 = v0 * Wc[2 * c0 + 1] + v1 * Wc[2 * (c0 + 1) + 1] + v2 * Wc[2 * (c0 + 2) + 1] + v3 * Wc[2 * (c0 + 3) + 1];
    }
    l0 += __shfl_xor(l0, 8); l1 += __shfl_xor(l1, 8);
    l0 += __shfl_xor(l0, 4); l1 += __shfl_xor(l1, 4);
    l0 += __shfl_xor(l0, 2); l1 += __shfl_xor(l1, 2);
    l0 += __shfl_xor(l0, 1); l1 += __shfl_xor(l1, 1);
    if (lane == 0) {
        outbuf[(size_t)node * 2 + 0] = l0 + bc[0];
        outbuf[(size_t)node * 2 + 1] = l1 + bc[1];
    }
}

extern "C" void kernel_launch(void* const* d_in, const int* in_sizes, int n_in,
                              void* d_out, int out_size, void* d_ws, size_t ws_size,
                              hipStream_t stream) {
    const float* x    = (const float*)d_in[0];
    const int*   ei   = (const int*)d_in[1];
    const float* Wp   = (const float*)d_in[2];
    const float* bp   = (const float*)d_in[3];
    const float* W1l  = (const float*)d_in[4];
    const float* b1l  = (const float*)d_in[5];
    const float* W1r  = (const float*)d_in[6];
    const float* bn1g = (const float*)d_in[7];
    const float* bn1b = (const float*)d_in[8];
    const float* bn1m = (const float*)d_in[9];
    const float* bn1v = (const float*)d_in[10];
    const float* Wsk  = (const float*)d_in[11];
    const float* bsk  = (const float*)d_in[12];
    const float* W2l  = (const float*)d_in[13];
    const float* b2l  = (const float*)d_in[14];
    const float* W2r  = (const float*)d_in[15];
    const float* bn2g = (const float*)d_in[16];
    const float* bn2b = (const float*)d_in[17];
    const float* bn2m = (const float*)d_in[18];
    const float* bn2v = (const float*)d_in[19];
    const float* W3l  = (const float*)d_in[20];
    const float* b3l  = (const float*)d_in[21];
    const float* W3r  = (const float*)d_in[22];
    const float* Wc   = (const float*)d_in[23];
    const float* bc   = (const float*)d_in[24];

    const int* src = ei;
    const int* dst = ei + NE;

    char* ws = (char*)d_ws;
    size_t o = 0;
    auto alloc = [&](size_t b) -> char* {
        char* p = ws + o;
        o = (o + b + 255) & ~(size_t)255;
        return p;
    };
    int* deg    = (int*)alloc((size_t)NN * 4);
    int* inc    = (int*)alloc((size_t)NN * 4);
    int* bsum   = (int*)alloc(256 * 4);
    int* rowptr = (int*)alloc((NN + 1) * 4);
    int* pos    = (int*)alloc((size_t)NN * 4);
    int* csr    = (int*)alloc((size_t)NE * 4);
    unsigned short* xcat = (unsigned short*)alloc((size_t)NN * 256 * 2);  // [mean1|xb]
    unsigned short* h1   = (unsigned short*)alloc((size_t)NN * 256 * 2);
    unsigned short* h2   = (unsigned short*)alloc((size_t)NN * 128 * 2);
    unsigned short* G    = (unsigned short*)alloc((size_t)NN * 256 * 2);  // [P|R] per layer
    unsigned short* Wf1  = (unsigned short*)alloc((size_t)256 * 256 * 2);
    unsigned short* Wf2  = (unsigned short*)alloc((size_t)256 * 256 * 2);
    unsigned short* Wf3  = (unsigned short*)alloc((size_t)128 * 128 * 2);
    float* c1 = (float*)alloc(256 * 4);
    float* c2 = (float*)alloc(128 * 4);
    float* c3 = (float*)alloc(64 * 4);

    float* outbuf = (float*)d_out;  // logits [NN][2] then emb [NN][64]

    // prep (also zeroes deg ahead of k_count)
    k_xcast<<<6250, 256, 0, stream>>>(x, xcat, deg);
    k_prep_all<<<72, 256, 0, stream>>>(Wp, bp, W1l, b1l, W1r, bn1g, bn1b, bn1m, bn1v,
                                       Wsk, bsk, W2l, b2l, W2r, bn2g, bn2b, bn2m, bn2v,
                                       W3l, b3l, W3r, Wf1, Wf2, Wf3, c1, c2, c3);

    // CSR build (XCD-sliced)
    k_count<<<1024, 256, 0, stream>>>(dst, deg);
    k_scan1<<<196, 256, 0, stream>>>(deg, inc, bsum);
    k_scan2<<<1, 256, 0, stream>>>(bsum);
    k_scan3<<<196, 256, 0, stream>>>(inc, deg, bsum, rowptr, pos);
    k_scatter<<<1024, 256, 0, stream>>>(src, dst, pos, csr);

    // layer 1: mean(xb) into xcat cols 0..127; h1 = relu([mean|xb] @ Wf1 + c1)
    k_aggx<<<12500, 256, 0, stream>>>(rowptr, csr, xcat);
    k_gemm<256, 256, true><<<dim3(391, 4), 256, 0, stream>>>(xcat, Wf1, c1, h1);

    // layer 2: [P2|R2] = h1 @ Wf2 ; h2 = relu(mean(P2) + R2 + c2)
    k_gemm<256, 256, false><<<dim3(391, 4), 256, 0, stream>>>(h1, Wf2, nullptr, G);
    k_agg2<<<12500, 256, 0, stream>>>(G, rowptr, csr, c2, h2);

    // layer 3: [P3|R3] = h2 @ Wf3 ; emb = mean(P3)+R3+c3 ; logits fused
    k_gemm<128, 128, false><<<dim3(391, 2), 256, 0, stream>>>(h2, Wf3, nullptr, G);
    k_agg_final<<<12500, 256, 0, stream>>>(G, rowptr, csr, c3, Wc, bc, outbuf);
}